// Round 1
// baseline (420.566 us; speedup 1.0000x reference)
//
#include <hip/hip_runtime.h>
#include <math.h>

#define OUT_HW 49          // 7*7 bins
#define NPOS   196         // 49 bins * 4 samples
#define N_ORI  8
#define HH     256
#define WW     256
#define CTOT   256
#define CPB    64          // channels (ct) per block
#define NVAL   (CPB * OUT_HW)   // 3136 pooled values per block

__global__ __launch_bounds__(256) void riroi_rotated_kernel(
    const float* __restrict__ feats,   // (B, CTOT, HH, WW)
    const float* __restrict__ rois,    // (n_rois, 6)
    float* __restrict__ out,           // (n_rois, CTOT, 7, 7)
    int n_rois)
{
    __shared__ int4   s_off[NPOS];   // 4 corner offsets within a channel plane
    __shared__ float4 s_w[NPOS];     // 4 bilinear weights * valid * 0.25
    __shared__ float  s_pool[NVAL];  // pooled[ct_local * 49 + bin]

    const int n       = blockIdx.x;
    const int ct_base = blockIdx.y * CPB;
    const int t       = threadIdx.x;

    // ---- per-RoI params (uniform across block; broadcast loads) ----
    const float* r = rois + n * 6;
    const int   b     = (int)r[0];
    const float cx    = r[1] * 0.25f;
    const float cy    = r[2] * 0.25f;
    const float rw    = fmaxf(r[3] * 0.25f, 1.0f);
    const float rh    = fmaxf(r[4] * 0.25f, 1.0f);
    const float theta = r[5];
    const float bin_h = rh / 7.0f;
    const float bin_w = rw / 7.0f;

    // ind_f = theta * 8 / (2*pi)  -- *8 exact in fp32, then one fp32 divide (matches np)
    const float ind_f = (theta * 8.0f) / 6.28318530717958647692f;
    const int   ind0  = (int)floorf(ind_f);
    const float l_var = ind_f - (float)ind0;
    const float r_var = 1.0f - l_var;
    const int   ind   = ((ind0 % N_ORI) + N_ORI) % N_ORI;
    const float cos_t = cosf(theta);   // CLOCKWISE=false -> th = theta
    const float sin_t = sinf(theta);

    // ---- precompute 196 sample positions: corner offsets + weights ----
    if (t < NPOS) {
        const int bin = t >> 2;       // 0..48
        const int s   = t & 3;        // gy*2 + gx
        const int ph  = bin / 7, pw = bin % 7;
        const int gy  = s >> 1,  gx = s & 1;
        const float yy = -rh * 0.5f + ((float)ph + ((float)gy + 0.5f) * 0.5f) * bin_h;
        const float xx = -rw * 0.5f + ((float)pw + ((float)gx + 0.5f) * 0.5f) * bin_w;
        const float y = yy * cos_t - xx * sin_t + cy;
        const float x = yy * sin_t + xx * cos_t + cx;
        const float valid =
            (y >= -1.0f && y <= (float)HH && x >= -1.0f && x <= (float)WW) ? 1.0f : 0.0f;
        const float yc = fmaxf(y, 0.0f);
        const float xc = fmaxf(x, 0.0f);
        int y0 = min((int)floorf(yc), HH - 1);
        int x0 = min((int)floorf(xc), WW - 1);
        const int y1 = min(y0 + 1, HH - 1);
        const int x1 = min(x0 + 1, WW - 1);
        const float ly = (y0 >= HH - 1) ? 0.0f : (yc - (float)y0);
        const float lx = (x0 >= WW - 1) ? 0.0f : (xc - (float)x0);
        const float hy = 1.0f - ly, hx = 1.0f - lx;
        const float sc = 0.25f * valid;   // fold sample-mean (/4) and validity into weights
        s_w[t]   = make_float4(hy * hx * sc, hy * lx * sc, ly * hx * sc, ly * lx * sc);
        s_off[t] = make_int4(y0 * WW + x0, y0 * WW + x1, y1 * WW + x0, y1 * WW + x1);
    }
    __syncthreads();

    const float* fbase = feats + (size_t)b * CTOT * (HH * WW);

    // ---- pooled[ct_local][bin] = mean over 4 samples of bilinear(feat[ct], pos) ----
    for (int v = t; v < NVAL; v += 256) {
        const int ct_local = v / OUT_HW;
        const int bin      = v - ct_local * OUT_HW;
        const float* plane = fbase + (size_t)(ct_base + ct_local) * (HH * WW);
        const int pb = bin * 4;
        float acc = 0.0f;
        #pragma unroll
        for (int s = 0; s < 4; ++s) {
            const int4   off = s_off[pb + s];
            const float4 w   = s_w[pb + s];
            acc += w.x * plane[off.x] + w.y * plane[off.y]
                 + w.z * plane[off.z] + w.w * plane[off.w];
        }
        s_pool[v] = acc;
    }
    __syncthreads();

    // ---- orientation mix + coalesced write ----
    float* obase = out + (size_t)n * (CTOT * OUT_HW) + (size_t)ct_base * OUT_HW;
    for (int v = t; v < NVAL; v += 256) {
        const int ct_local = v / OUT_HW;
        const int bin      = v - ct_local * OUT_HW;
        const int cl = ct_local >> 3;          // local c-group
        const int o  = ct_local & 7;           // orientation
        const int i0 = (o - ind + 8) & 7;      // idx
        const int i1 = (i0 + 1) & 7;           // idx_p
        const float val = r_var * s_pool[(cl * 8 + i0) * OUT_HW + bin]
                        + l_var * s_pool[(cl * 8 + i1) * OUT_HW + bin];
        obase[v] = val;
    }
}

extern "C" void kernel_launch(void* const* d_in, const int* in_sizes, int n_in,
                              void* d_out, int out_size, void* d_ws, size_t ws_size,
                              hipStream_t stream) {
    const float* feats = (const float*)d_in[0];
    const float* rois  = (const float*)d_in[1];
    float* out = (float*)d_out;
    const int n_rois = in_sizes[1] / 6;
    dim3 grid(n_rois, CTOT / CPB);
    riroi_rotated_kernel<<<grid, 256, 0, stream>>>(feats, rois, out, n_rois);
}